// Round 3
// baseline (91.232 us; speedup 1.0000x reference)
//
#include <hip/hip_runtime.h>
#include <stdint.h>

// Problem constants (fixed by the reference)
#define INF    8192
#define OUTF   8192
#define NOUT   64
#define NG     256          // 3-bit groups along input dim (INF/32)
#define BLK    512          // threads per block (8 waves)
#define COLS   32           // output columns per block
#define CP     16           // column pairs per block (each thread: 2 adjacent cols)
#define KC     32           // k-chunks per block (t>>4)
#define GPT    (NG / KC)    // groups per thread = 8

// padded x in LDS: +1 float4 per 64 float4 (1 KiB) chunk -> kc regions hit
// disjoint banks (shift of 4 banks per chunk)
#define XS4N   (INF / 4 + INF / 256)   // 2048 + 32 = 2080 float4

__device__ __forceinline__ void unpack_mac(unsigned r0, unsigned r1, unsigned r2,
                                           const float* xr, float& a0, float& a1) {
    #pragma unroll
    for (int i = 0; i < 32; ++i) {
        unsigned qv;
        if (i < 10)       qv = (r0 >> (3 * i)) & 7u;
        else if (i == 10) qv = ((r0 >> 30) & 3u) | ((r1 & 1u) << 2);
        else if (i < 21)  qv = (r1 >> (3 * (i - 11) + 1)) & 7u;
        else if (i == 21) qv = ((r1 >> 31) & 1u) | ((r2 & 3u) << 1);
        else              qv = (r2 >> (3 * (i - 22) + 2)) & 7u;
        if (i & 1) a1 += xr[i] * (float)qv;
        else       a0 += xr[i] * (float)qv;
    }
}

__global__ __launch_bounds__(BLK) void q3gemv(
    const float* __restrict__ x,       // f32 [INF]
    const int*   __restrict__ qw,      // [NG*3, OUTF] packed 3-bit
    const float* __restrict__ scales,  // f32 [OUTF]
    const float* __restrict__ zeros,   // f32 [OUTF]
    const float* __restrict__ bias,    // f32 [OUTF]
    const float* __restrict__ ow,      // f32 [OUTF, NOUT]
    const int*   __restrict__ oidx,    // [NOUT]
    float*       __restrict__ out)     // f32 [OUTF]
{
    __shared__ __align__(16) float4 xs4[XS4N];   // staged x, bank-staggered
    __shared__ float psum[KC][COLS + 1];
    __shared__ float xo[NOUT];
    __shared__ float wsum[BLK / 64];

    const int t     = threadIdx.x;
    const int cp    = t & (CP - 1);              // column pair 0..15
    const int kc    = t >> 4;                    // k-chunk 0..31
    const int obase = blockIdx.x * COLS;

    // ---- stage x into LDS (float4 coalesced, staggered), side-accumulate Sx ----
    float lsum = 0.f;
    const float4* xv = (const float4*)x;
    #pragma unroll
    for (int k = 0; k < INF / (BLK * 4); ++k) {  // 4 float4 loads/thread
        int v = t + k * BLK;
        float4 d = xv[v];
        xs4[v + (v >> 6)] = d;
        lsum += (d.x + d.y) + (d.z + d.w);
    }
    #pragma unroll
    for (int off = 32; off > 0; off >>= 1)
        lsum += __shfl_down(lsum, off, 64);
    if ((t & 63) == 0) wsum[t >> 6] = lsum;
    __syncthreads();

    // gather outlier x from (padded) LDS; visible to epilogue after 2nd barrier
    if (t < NOUT) {
        int i = oidx[t];
        xo[t] = ((const float*)xs4)[i + ((i >> 8) << 2)];
    }

    // ---- main loop: columns (obase+2cp, +1), groups [kc*GPT, kc*GPT+GPT) ----
    const unsigned* qp = (const unsigned*)qw + (size_t)(kc * GPT * 3) * OUTF + (obase + 2 * cp);
    uint2 c0 = *(const uint2*)qp;
    uint2 c1 = *(const uint2*)(qp + OUTF);
    uint2 c2 = *(const uint2*)(qp + 2 * OUTF);

    float aA0 = 0.f, aA1 = 0.f, aB0 = 0.f, aB1 = 0.f;
    const int xbase = kc * 65;                   // padded float4 index of this chunk

    #pragma unroll 2
    for (int gg = 0; gg < GPT; ++gg) {
        // prefetch next group's packed data (depth 1)
        const unsigned* qn = qp + ((gg + 1 < GPT) ? (size_t)3 * OUTF : 0);
        uint2 n0 = *(const uint2*)qn;
        uint2 n1 = *(const uint2*)(qn + OUTF);
        uint2 n2 = *(const uint2*)(qn + 2 * OUTF);

        float xr[32];
        #pragma unroll
        for (int j = 0; j < 8; ++j) {            // 8 x ds_read_b128, conflict-free
            float4 d = xs4[xbase + gg * 8 + j];
            xr[4 * j + 0] = d.x; xr[4 * j + 1] = d.y;
            xr[4 * j + 2] = d.z; xr[4 * j + 3] = d.w;
        }

        unpack_mac(c0.x, c1.x, c2.x, xr, aA0, aA1);  // even column
        unpack_mac(c0.y, c1.y, c2.y, xr, aB0, aB1);  // odd column

        c0 = n0; c1 = n1; c2 = n2;
        qp += (size_t)3 * OUTF;
    }
    psum[kc][2 * cp + 0] = aA0 + aA1;
    psum[kc][2 * cp + 1] = aB0 + aB1;
    __syncthreads();

    // ---- epilogue: 32 threads finalize the block's 32 columns ----
    if (t < COLS) {
        const int oo = obase + t;
        float a = 0.f;
        #pragma unroll
        for (int k = 0; k < KC; ++k) a += psum[k][t];

        float sx = 0.f;
        #pragma unroll
        for (int w = 0; w < BLK / 64; ++w) sx += wsum[w];

        float od = 0.f;
        const float4* wv = (const float4*)(ow + (size_t)oo * NOUT);
        #pragma unroll
        for (int b = 0; b < 16; ++b) {
            float4 u = wv[b];
            od += u.x * xo[4 * b + 0] + u.y * xo[4 * b + 1]
                + u.z * xo[4 * b + 2] + u.w * xo[4 * b + 3];
        }

        out[oo] = scales[oo] * a - zeros[oo] * sx + bias[oo] + od;
    }
}

extern "C" void kernel_launch(void* const* d_in, const int* in_sizes, int n_in,
                              void* d_out, int out_size, void* d_ws, size_t ws_size,
                              hipStream_t stream) {
    const float* x  = (const float*)d_in[0];
    const int*   qw = (const int*)d_in[1];
    const float* sc = (const float*)d_in[2];
    const float* zr = (const float*)d_in[3];
    const float* bs = (const float*)d_in[4];
    const float* ow = (const float*)d_in[5];
    const int*   oi = (const int*)d_in[6];
    float*       y  = (float*)d_out;

    q3gemv<<<OUTF / COLS, BLK, 0, stream>>>(x, qw, sc, zr, bs, ow, oi, y);
}

// Round 4
// 86.767 us; speedup vs baseline: 1.0515x; 1.0515x over previous
//
#include <hip/hip_runtime.h>
#include <stdint.h>

// Problem constants (fixed by the reference)
#define INF    8192
#define OUTF   8192
#define NOUT   64
#define NG     256          // 3-bit groups along input dim (INF/32)
#define BLK    1024         // threads per block (16 waves -> 4 waves/SIMD)
#define COLS   32           // output columns per block
#define CP     16           // column pairs per block (each thread: 2 adjacent cols)
#define KC     64           // k-chunks per block (t>>4)
#define GPT    (NG / KC)    // groups per thread = 4

// padded x in LDS: +1 float4 per 32 float4 chunk -> the 4 kc-regions a wave
// touches land on banks {0,4,8,12} (perfect spread; was 2-way aliased)
#define XS4N   (INF / 4 + INF / 128)   // 2048 + 64 = 2112 float4

__device__ __forceinline__ void unpack_mac(unsigned r0, unsigned r1, unsigned r2,
                                           const float* xr, float& a0, float& a1) {
    #pragma unroll
    for (int i = 0; i < 32; ++i) {
        unsigned qv;
        if (i < 10)       qv = (r0 >> (3 * i)) & 7u;          // v_bfe_u32
        else if (i == 10) qv = ((r0 >> 30) & 3u) | ((r1 & 1u) << 2);
        else if (i < 21)  qv = (r1 >> (3 * (i - 11) + 1)) & 7u;
        else if (i == 21) qv = ((r1 >> 31) & 1u) | ((r2 & 3u) << 1);
        else              qv = (r2 >> (3 * (i - 22) + 2)) & 7u;
        if (i & 1) a1 += xr[i] * (float)qv;                   // v_cvt + v_fmac
        else       a0 += xr[i] * (float)qv;
    }
}

__global__ __launch_bounds__(BLK) void q3gemv(
    const float* __restrict__ x,       // f32 [INF]
    const int*   __restrict__ qw,      // [NG*3, OUTF] packed 3-bit
    const float* __restrict__ scales,  // f32 [OUTF]
    const float* __restrict__ zeros,   // f32 [OUTF]
    const float* __restrict__ bias,    // f32 [OUTF]
    const float* __restrict__ ow,      // f32 [OUTF, NOUT]
    const int*   __restrict__ oidx,    // [NOUT]
    float*       __restrict__ out)     // f32 [OUTF]
{
    __shared__ __align__(16) float4 xs4[XS4N];   // staged x, bank-staggered
    __shared__ float psum[KC][COLS + 1];
    __shared__ float xo[NOUT];
    __shared__ float wsum[BLK / 64];

    const int t     = threadIdx.x;
    const int cp    = t & (CP - 1);              // column pair 0..15
    const int kc    = t >> 4;                    // k-chunk 0..63
    const int obase = blockIdx.x * COLS;

    // ---- stage x into LDS (float4 coalesced, staggered), side-accumulate Sx ----
    float lsum = 0.f;
    const float4* xv = (const float4*)x;
    #pragma unroll
    for (int k = 0; k < INF / (BLK * 4); ++k) {  // 2 float4 loads/thread
        int v = t + k * BLK;
        float4 d = xv[v];
        xs4[v + (v >> 5)] = d;
        lsum += (d.x + d.y) + (d.z + d.w);
    }
    #pragma unroll
    for (int off = 32; off > 0; off >>= 1)
        lsum += __shfl_down(lsum, off, 64);
    if ((t & 63) == 0) wsum[t >> 6] = lsum;
    __syncthreads();

    // gather outlier x from (padded) LDS; visible to epilogue after 2nd barrier
    if (t < NOUT) {
        int i = oidx[t];
        xo[t] = ((const float*)xs4)[i + ((i >> 7) << 2)];
    }

    // ---- main loop: columns (obase+2cp, +1), groups [kc*GPT, kc*GPT+GPT) ----
    const unsigned* qp = (const unsigned*)qw + (size_t)(kc * GPT * 3) * OUTF + (obase + 2 * cp);
    uint2 c0 = *(const uint2*)qp;
    uint2 c1 = *(const uint2*)(qp + OUTF);
    uint2 c2 = *(const uint2*)(qp + 2 * OUTF);

    float aA0 = 0.f, aA1 = 0.f, aB0 = 0.f, aB1 = 0.f;
    const int xbase = kc * 32 + kc;              // padded float4 index of this chunk

    #pragma unroll
    for (int gg = 0; gg < GPT; ++gg) {
        // prefetch next group's packed data (depth 1)
        const unsigned* qn = qp + ((gg + 1 < GPT) ? (size_t)3 * OUTF : 0);
        uint2 n0 = *(const uint2*)qn;
        uint2 n1 = *(const uint2*)(qn + OUTF);
        uint2 n2 = *(const uint2*)(qn + 2 * OUTF);

        float xr[32];
        #pragma unroll
        for (int j = 0; j < 8; ++j) {            // 8 x ds_read_b128, conflict-free
            float4 d = xs4[xbase + gg * 8 + j];
            xr[4 * j + 0] = d.x; xr[4 * j + 1] = d.y;
            xr[4 * j + 2] = d.z; xr[4 * j + 3] = d.w;
        }

        unpack_mac(c0.x, c1.x, c2.x, xr, aA0, aA1);  // even column
        unpack_mac(c0.y, c1.y, c2.y, xr, aB0, aB1);  // odd column

        c0 = n0; c1 = n1; c2 = n2;
        qp += (size_t)3 * OUTF;
    }
    psum[kc][2 * cp + 0] = aA0 + aA1;
    psum[kc][2 * cp + 1] = aB0 + aB1;
    __syncthreads();

    // ---- epilogue: 32 threads finalize the block's 32 columns ----
    if (t < COLS) {
        const int oo = obase + t;
        float a = 0.f;
        #pragma unroll
        for (int k = 0; k < KC; ++k) a += psum[k][t];

        float sx = 0.f;
        #pragma unroll
        for (int w = 0; w < BLK / 64; ++w) sx += wsum[w];

        float od = 0.f;
        const float4* wv = (const float4*)(ow + (size_t)oo * NOUT);
        #pragma unroll
        for (int b = 0; b < 16; ++b) {
            float4 u = wv[b];
            od += u.x * xo[4 * b + 0] + u.y * xo[4 * b + 1]
                + u.z * xo[4 * b + 2] + u.w * xo[4 * b + 3];
        }

        out[oo] = scales[oo] * a - zeros[oo] * sx + bias[oo] + od;
    }
}

extern "C" void kernel_launch(void* const* d_in, const int* in_sizes, int n_in,
                              void* d_out, int out_size, void* d_ws, size_t ws_size,
                              hipStream_t stream) {
    const float* x  = (const float*)d_in[0];
    const int*   qw = (const int*)d_in[1];
    const float* sc = (const float*)d_in[2];
    const float* zr = (const float*)d_in[3];
    const float* bs = (const float*)d_in[4];
    const float* ow = (const float*)d_in[5];
    const int*   oi = (const int*)d_in[6];
    float*       y  = (float*)d_out;

    q3gemv<<<OUTF / COLS, BLK, 0, stream>>>(x, qw, sc, zr, bs, ow, oi, y);
}